// Round 4
// baseline (161.793 us; speedup 1.0000x reference)
//
#include <hip/hip_runtime.h>
#include <hip/hip_bf16.h>
#include <math.h>

typedef __attribute__((ext_vector_type(8))) __bf16 bf16x8;
typedef __attribute__((ext_vector_type(4))) float f32x4;
typedef __attribute__((ext_vector_type(8))) unsigned short u16x8;

__device__ __forceinline__ float sigmoid_f(float v) {
  return __builtin_amdgcn_rcpf(1.f + __expf(-v));
}
__device__ __forceinline__ float tanh_f(float z) {
  float az = fabsf(z);
  float e = __expf(-2.f * az);
  float t = (1.f - e) * __builtin_amdgcn_rcpf(1.f + e);
  return copysignf(t, z);
}
__device__ __forceinline__ bf16x8 cvt8(float4 a, float4 b) {
  bf16x8 r;
  r[0] = (__bf16)a.x; r[1] = (__bf16)a.y; r[2] = (__bf16)a.z; r[3] = (__bf16)a.w;
  r[4] = (__bf16)b.x; r[5] = (__bf16)b.y; r[6] = (__bf16)b.z; r[7] = (__bf16)b.w;
  return r;
}

// Pack W_x/W_h fp32 -> bf16 into 12 half-matrix blocks of 16KB (col-half ch
// major, then pass m). 16B chunk id t = (ch*6 + m)*1024 + c2,
// c2 = (nt*4+kt)*64 + lane. Chunk holds
// W[ro + ch*64 + nt*16 + (lane&15)][kt*32 + (lane>>4)*8 .. +7].
// Phase q (= ch*3 + s) stages the consecutive pair {m=2s, m=2s+1} = 32KB.
// global_load_lds staging (wave-uniform base + lane*16) lands exactly where the
// ds_read_b128 B-frag reads expect it: both wave-linear, 0 bank conflicts.
// pass order m: 0 Wx_r, 1 Wh_r, 2 Wh_h, 3 Wx_h, 4 Wx_u, 5 Wh_u
__global__ void pack_weights_kernel(const float* __restrict__ Wx,
                                    const float* __restrict__ Wh,
                                    unsigned short* __restrict__ wp) {
  int t = blockIdx.x * 256 + threadIdx.x;
  if (t >= 12288) return;          // 2 halves * 6 matrices * 1024 chunks
  int ch = t / 6144;
  int r  = t - ch * 6144;
  int m  = r >> 10;
  int c2 = r & 1023;
  int nt = c2 >> 8;
  int kt = (c2 >> 6) & 3;
  int lane = c2 & 63;
  const float* src; int ro;
  switch (m) {
    case 0: src = Wx; ro = 128; break;
    case 1: src = Wh; ro = 128; break;
    case 2: src = Wh; ro = 256; break;
    case 3: src = Wx; ro = 256; break;
    case 4: src = Wx; ro = 0;   break;
    default: src = Wh; ro = 0;  break;
  }
  const float* p = src + (ro + ch * 64 + nt * 16 + (lane & 15)) * 128
                       + kt * 32 + (lane >> 4) * 8;
  *(bf16x8*)(wp + t * 8) = cvt8(*(const float4*)p, *(const float4*)(p + 4));
}

// 512 threads = 8 waves, wave owns 16 rows (block: 128 rows).
// 6 phases of 32KB (2 half-matrices each), double-buffered in 64KB LDS,
// 1 fence per phase. 512 blocks -> 2 blocks/CU, whole grid co-resident.
__global__ __launch_bounds__(512, 4) void augru_kernel(
    const float* __restrict__ x, const float* __restrict__ hp,
    const float* __restrict__ att, const unsigned short* __restrict__ wp,
    const float* __restrict__ bx, const float* __restrict__ bh,
    float* __restrict__ out) {
  __shared__ __align__(16) unsigned short wlds[2][16384];  // 2 x 32KB
  const int tid  = threadIdx.x;
  const int wave = tid >> 6;
  const int lane = tid & 63;
  const int quad = lane >> 4;
  const int l15  = lane & 15;
  const int rb   = blockIdx.x * 128 + wave * 16;  // this wave's 16 rows

  // stage phase q's 32KB into buf q&1: 4 rounds x 512 threads x 16B, linear
  auto stage = [&](int q) {
#pragma unroll
    for (int i = 0; i < 4; ++i) {
      const unsigned short* g = wp + q * 16384 + (i * 512 + tid) * 8;
      unsigned short* l = &wlds[q & 1][(i * 512 + wave * 64) * 8];  // HW adds lane*16B
      __builtin_amdgcn_global_load_lds(
          (const __attribute__((address_space(1))) void*)g,
          (__attribute__((address_space(3))) void*)l, 16, 0, 0);
    }
  };

  stage(0);  // in flight while we build A-fragments

  // A-fragments: global fp32 -> bf16 regs, held for the whole kernel.
  // A[m = l15][k = quad*8+j] per 16x16x32 K-tile.
  bf16x8 xf[4], hf[4];
  {
    const float* xr = x  + (rb + l15) * 128;
    const float* hr = hp + (rb + l15) * 128;
#pragma unroll
    for (int kt = 0; kt < 4; ++kt) {
      int off = kt * 32 + quad * 8;
      xf[kt] = cvt8(*(const float4*)(xr + off), *(const float4*)(xr + off + 4));
      hf[kt] = cvt8(*(const float4*)(hr + off), *(const float4*)(hr + off + 4));
    }
  }
  float atts[4];
#pragma unroll
  for (int r = 0; r < 4; ++r) atts[r] = att[rb + quad * 4 + r];

  f32x4 acc[4], keep[4];

  // one half-matrix gemm: 16 ds_read_b128 + 16 MFMA, wave-linear (0 conflicts)
  auto gemm = [&](int b, int j, const bf16x8 (&af)[4]) {
    __builtin_amdgcn_s_setprio(1);
#pragma unroll
    for (int nt = 0; nt < 4; ++nt)
#pragma unroll
      for (int kt = 0; kt < 4; ++kt) {
        bf16x8 bfrag = *(const bf16x8*)&wlds[b][j * 8192 + ((nt * 4 + kt) * 64 + lane) * 8];
        acc[nt] = __builtin_amdgcn_mfma_f32_16x16x32_bf16(af[kt], bfrag, acc[nt], 0, 0, 0);
      }
    __builtin_amdgcn_s_setprio(0);
  };
  auto fence = [&]() {
    asm volatile("s_waitcnt vmcnt(0)" ::: "memory");
    __syncthreads();
  };

  fence();  // phase-0 weights resident; A-frag loads also drained

#pragma unroll
  for (int ch = 0; ch < 2; ++ch) {
    const int q0 = ch * 3;   // phase base; buffer for phase q is q&1
    const int cb = ch * 64;  // column base
#pragma unroll
    for (int nt = 0; nt < 4; ++nt) acc[nt] = (f32x4)0.f;

    // --- phase q0: {Wx_r, Wh_r} -> r
    stage(q0 + 1);
    gemm(q0 & 1, 0, xf);
    gemm(q0 & 1, 1, hf);
#pragma unroll
    for (int nt = 0; nt < 4; ++nt) {
      int col = cb + nt * 16 + l15;
      float br = bx[128 + col] + bh[128 + col];
#pragma unroll
      for (int r = 0; r < 4; ++r) {
        keep[nt][r] = sigmoid_f(acc[nt][r] + br);
        acc[nt][r] = 0.f;
      }
    }
    fence();

    // --- phase q0+1: {Wh_h, Wx_h} -> h_tilde
    stage(q0 + 2);
    gemm((q0 + 1) & 1, 0, hf);   // h . Wh_h
#pragma unroll
    for (int nt = 0; nt < 4; ++nt) {
      int col = cb + nt * 16 + l15;
      float bhh = bh[256 + col];
#pragma unroll
      for (int r = 0; r < 4; ++r) {
        keep[nt][r] = keep[nt][r] * (acc[nt][r] + bhh);  // t = r * (g + bh_h)
        acc[nt][r] = 0.f;
      }
    }
    gemm((q0 + 1) & 1, 1, xf);   // x . Wx_h
#pragma unroll
    for (int nt = 0; nt < 4; ++nt) {
      int col = cb + nt * 16 + l15;
      float bxh = bx[256 + col];
#pragma unroll
      for (int r = 0; r < 4; ++r) {
        keep[nt][r] = tanh_f(acc[nt][r] + bxh + keep[nt][r]);
        acc[nt][r] = 0.f;
      }
    }
    fence();

    // --- phase q0+2: {Wx_u, Wh_u} -> u, blend, store this col-half
    if (q0 + 3 < 6) stage(q0 + 3);
    gemm((q0 + 2) & 1, 0, xf);
    gemm((q0 + 2) & 1, 1, hf);
#pragma unroll
    for (int nt = 0; nt < 4; ++nt) {
      int col = cb + nt * 16 + l15;
      float bu = bx[col] + bh[col];
#pragma unroll
      for (int r = 0; r < 4; ++r) {
        int row = rb + quad * 4 + r;
        float u  = sigmoid_f(acc[nt][r] + bu);
        float ua = atts[r] * u;
        float h0 = hp[row * 128 + col];
        out[row * 128 + col] = fmaf(ua, keep[nt][r] - h0, h0);  // (1-ua)*h0 + ua*ht
      }
    }
    if (q0 + 3 < 6) fence();
  }
}

extern "C" void kernel_launch(void* const* d_in, const int* in_sizes, int n_in,
                              void* d_out, int out_size, void* d_ws, size_t ws_size,
                              hipStream_t stream) {
  const float* x   = (const float*)d_in[0];
  const float* hpv = (const float*)d_in[1];
  const float* att = (const float*)d_in[2];
  const float* Wx  = (const float*)d_in[3];
  const float* bx  = (const float*)d_in[4];
  const float* Wh  = (const float*)d_in[5];
  const float* bh  = (const float*)d_in[6];
  float* out = (float*)d_out;
  unsigned short* wp = (unsigned short*)d_ws;  // 196,608 B of scratch

  pack_weights_kernel<<<48, 256, 0, stream>>>(Wx, Wh, wp);
  augru_kernel<<<512, 512, 0, stream>>>(x, hpv, att, wp, bx, bh, out);
}